// Round 7
// baseline (19.196 us; speedup 1.0000x reference)
//
#include <hip/hip_runtime.h>

#define VOC 64
#define TPB 256
#define WAVES (TPB / 64)
#define RPW 8                  // rows per wave per iteration (8 lanes/row)
#define NITER 4
#define ROWS_PER_BLOCK (WAVES * RPW * NITER)   // 128

typedef float f32x4 __attribute__((ext_vector_type(4)));

// Single fused dispatch, half-row speculative read.
//  LUT: lut[v] = (c0*v + a0) % 64, a0 = argmax(W[v,0:64]+b[0:64]),
//       c0 = argmax(W[v,64:128]+b[64:128]); -1 when c0 == 0 (zero row).
//  Each row (64 floats) is handled by 8 lanes. Phase A reads the first
//  128 B; rows whose 1.0 isn't there (P=1/2) read the second 128 B in
//  phase B. Expected input traffic: 192 B/row instead of 256 B (-12.5%
//  total bytes). Phase-A-resolved rows store BEFORE the phase-B wait.
__global__ __launch_bounds__(TPB) void flow_fused_kernel(
    const float* __restrict__ in,
    const float* __restrict__ W,
    const float* __restrict__ bias,
    float* __restrict__ out,
    int n_rows)
{
    __shared__ int s_lut[VOC];
    const int tid = threadIdx.x;

    // ---- 1. issue LUT source loads FIRST (256 threads, 4 per vocab row) ----
    const int v = tid >> 2;
    const int q = tid & 3;
    const f32x4* rowL = reinterpret_cast<const f32x4*>(W + v * 2 * VOC) + q * 4;
    const f32x4* rowS = rowL + (VOC / 4);   // +64 floats
    const f32x4* b4   = reinterpret_cast<const f32x4*>(bias);
    f32x4 wL[4], wS[4], bL[4], bS[4];
    #pragma unroll
    for (int k = 0; k < 4; ++k) {
        wL[k] = rowL[k];
        wS[k] = rowS[k];
        bL[k] = b4[q * 4 + k];
        bS[k] = b4[16 + q * 4 + k];
    }

    // ---- 2. phase-A loads: first 128 B of each row (stay in flight) ----
    const int lane = tid & 63;
    const int wav  = tid >> 6;
    const int rg   = lane >> 3;          // row-group within wave (0..7)
    const int sub  = lane & 7;           // lane's quarter-of-half-row
    const int row0 = blockIdx.x * ROWS_PER_BLOCK + wav * RPW + rg;

    const f32x4* in4  = reinterpret_cast<const f32x4*>(in);
    f32x4*       out4 = reinterpret_cast<f32x4*>(out);

    f32x4 xa[NITER];
    #pragma unroll
    for (int i = 0; i < NITER; ++i) {
        int r = row0 + i * (WAVES * RPW);
        if (r < n_rows) xa[i] = __builtin_nontemporal_load(in4 + (size_t)r * 16 + sub);
        else            xa[i] = (f32x4){0.f, 0.f, 0.f, 0.f};
    }

    // ---- 3. LUT build (waitcnt drains only W/b; phase-A still airborne) ----
    {
        float bvL = -3.402823466e+38f; int biL = 0;
        float bvS = -3.402823466e+38f; int biS = 0;
        #pragma unroll
        for (int k = 0; k < 4; ++k) {
            float x0 = wL[k].x + bL[k].x, x1 = wL[k].y + bL[k].y;
            float x2 = wL[k].z + bL[k].z, x3 = wL[k].w + bL[k].w;
            float y0 = wS[k].x + bS[k].x, y1 = wS[k].y + bS[k].y;
            float y2 = wS[k].z + bS[k].z, y3 = wS[k].w + bS[k].w;
            int ib = q * 16 + k * 4;
            // ascending index + strict > keeps first occurrence (jnp.argmax)
            if (x0 > bvL) { bvL = x0; biL = ib;     }
            if (x1 > bvL) { bvL = x1; biL = ib + 1; }
            if (x2 > bvL) { bvL = x2; biL = ib + 2; }
            if (x3 > bvL) { bvL = x3; biL = ib + 3; }
            if (y0 > bvS) { bvS = y0; biS = ib;     }
            if (y1 > bvS) { bvS = y1; biS = ib + 1; }
            if (y2 > bvS) { bvS = y2; biS = ib + 2; }
            if (y3 > bvS) { bvS = y3; biS = ib + 3; }
        }
        #pragma unroll
        for (int off = 1; off < 4; off <<= 1) {
            float ov = __shfl_xor(bvL, off, 4);
            int   oi = __shfl_xor(biL, off, 4);
            if (ov > bvL || (ov == bvL && oi < biL)) { bvL = ov; biL = oi; }
            ov = __shfl_xor(bvS, off, 4);
            oi = __shfl_xor(biS, off, 4);
            if (ov > bvS || (ov == bvS && oi < biS)) { bvS = ov; biS = oi; }
        }
        if (q == 0) s_lut[v] = (biS == 0) ? -1 : (biS * v + biL) & (VOC - 1);
    }
    __syncthreads();

    const int e0 = sub << 2;        // this lane's elems in [0,32)
    const int e1 = 32 + e0;         // this lane's elems in [32,64)

    #pragma unroll
    for (int i = 0; i < NITER; ++i) {
        int r = row0 + i * (WAVES * RPW);
        bool valid = (r < n_rows);
        f32x4 x = xa[i];

        int li = -1;                      // local index of the 1.0 (0..3)
        if (x.x > 0.5f) li = 0;
        if (x.y > 0.5f) li = 1;
        if (x.z > 0.5f) li = 2;
        if (x.w > 0.5f) li = 3;
        unsigned long long mh = __ballot(li >= 0);
        unsigned long long m0 = __ballot(li >= 0 && (li & 1));
        unsigned long long m1 = __ballot(li >= 2);
        unsigned gm = (unsigned)((mh >> (rg * 8)) & 0xFFull);
        bool found = (gm != 0);

        // ---- resolved in phase A: store immediately (before phase-B wait) ----
        if (valid && found) {
            int wl   = __builtin_ctz(gm);
            int wbit = rg * 8 + wl;
            int liw  = (int)((m0 >> wbit) & 1ull) | ((int)((m1 >> wbit) & 1ull) << 1);
            int bi   = (wl << 2) | liw;
            int oidx = s_lut[bi];              // -1 => zero row
            f32x4 v0, v1;
            v0.x = (oidx == e0)     ? 1.0f : 0.0f;
            v0.y = (oidx == e0 + 1) ? 1.0f : 0.0f;
            v0.z = (oidx == e0 + 2) ? 1.0f : 0.0f;
            v0.w = (oidx == e0 + 3) ? 1.0f : 0.0f;
            v1.x = (oidx == e1)     ? 1.0f : 0.0f;
            v1.y = (oidx == e1 + 1) ? 1.0f : 0.0f;
            v1.z = (oidx == e1 + 2) ? 1.0f : 0.0f;
            v1.w = (oidx == e1 + 3) ? 1.0f : 0.0f;
            __builtin_nontemporal_store(v0, out4 + (size_t)r * 16 + sub);
            __builtin_nontemporal_store(v1, out4 + (size_t)r * 16 + 8 + sub);
        }

        // ---- phase B: fetch second half only for unresolved rows ----
        bool needB = valid && !found;
        f32x4 xb = (f32x4){0.f, 0.f, 0.f, 0.f};
        if (needB) xb = __builtin_nontemporal_load(in4 + (size_t)r * 16 + 8 + sub);

        int liB = -1;
        if (xb.x > 0.5f) liB = 0;
        if (xb.y > 0.5f) liB = 1;
        if (xb.z > 0.5f) liB = 2;
        if (xb.w > 0.5f) liB = 3;
        unsigned long long mhB = __ballot(liB >= 0);
        unsigned long long m0B = __ballot(liB >= 0 && (liB & 1));
        unsigned long long m1B = __ballot(liB >= 2);

        if (needB) {
            unsigned gmB = (unsigned)((mhB >> (rg * 8)) & 0xFFull);
            int oidx = -1;
            if (gmB) {
                int wl   = __builtin_ctz(gmB);
                int wbit = rg * 8 + wl;
                int liw  = (int)((m0B >> wbit) & 1ull) | ((int)((m1B >> wbit) & 1ull) << 1);
                int bi   = 32 + ((wl << 2) | liw);
                oidx = s_lut[bi];
            }
            f32x4 v0, v1;
            v0.x = (oidx == e0)     ? 1.0f : 0.0f;
            v0.y = (oidx == e0 + 1) ? 1.0f : 0.0f;
            v0.z = (oidx == e0 + 2) ? 1.0f : 0.0f;
            v0.w = (oidx == e0 + 3) ? 1.0f : 0.0f;
            v1.x = (oidx == e1)     ? 1.0f : 0.0f;
            v1.y = (oidx == e1 + 1) ? 1.0f : 0.0f;
            v1.z = (oidx == e1 + 2) ? 1.0f : 0.0f;
            v1.w = (oidx == e1 + 3) ? 1.0f : 0.0f;
            __builtin_nontemporal_store(v0, out4 + (size_t)r * 16 + sub);
            __builtin_nontemporal_store(v1, out4 + (size_t)r * 16 + 8 + sub);
        }
    }
}

extern "C" void kernel_launch(void* const* d_in, const int* in_sizes, int n_in,
                              void* d_out, int out_size, void* d_ws, size_t ws_size,
                              hipStream_t stream) {
    const float* inputs = (const float*)d_in[0];  // (B, L, 64) f32 one-hot
    const float* W      = (const float*)d_in[1];  // (64, 128) f32
    const float* b      = (const float*)d_in[2];  // (128,) f32
    float* out = (float*)d_out;

    int n_rows = in_sizes[0] / VOC;               // B*L = 131072
    int blocks = (n_rows + ROWS_PER_BLOCK - 1) / ROWS_PER_BLOCK;  // 1024

    flow_fused_kernel<<<blocks, TPB, 0, stream>>>(inputs, W, b, out, n_rows);
}